// Round 18
// baseline (298.772 us; speedup 1.0000x reference)
//
#include <hip/hip_runtime.h>
#include <hip/hip_fp16.h>

typedef __attribute__((ext_vector_type(8))) short short8;
typedef __attribute__((ext_vector_type(4))) short short4v;
typedef __attribute__((ext_vector_type(4))) unsigned int uint4v;
typedef __attribute__((ext_vector_type(4))) float floatx4;
typedef __attribute__((ext_vector_type(16))) float floatx16;
typedef __fp16 fp16x2_raw __attribute__((ext_vector_type(2)));   // cvt_pkrtz ret
typedef _Float16 h2 __attribute__((ext_vector_type(2)));
typedef _Float16 half8 __attribute__((ext_vector_type(8)));

__device__ __forceinline__ unsigned short f2h(float x) {
  _Float16 h = (_Float16)x;
  return __builtin_bit_cast(unsigned short, h);
}
__device__ __forceinline__ float h2f(unsigned short u) {
  return (float)__builtin_bit_cast(_Float16, u);
}

// ---------------------------------------------------------------------
// Pack extended weights [W | root] into MFMA B-fragment order (flat i),
// as FP16. K-dim order IDENTITY. K2=0 packs a 64x64 matrix from root.
// ---------------------------------------------------------------------
__device__ __forceinline__ void pack_b_dev(
    const float* __restrict__ W, const float* __restrict__ root,
    unsigned short* __restrict__ Bpk, int K2, int i) {
  int j = i & 7;
  int lane = (i >> 3) & 63;
  int rest = i >> 9;            // kc*4 + wv
  int wv = rest & 3, kc = rest >> 2;
  int o = wv * 16 + (lane & 15);
  int p = kc * 32 + ((lane >> 4) & 3) * 8 + j;   // flat K position
  int k = p >> 6, q6 = p & 63;
  float v = (k < K2) ? W[(k << 12) + (q6 << 6) + o] : root[(q6 << 6) + o];
  Bpk[i] = f2h(v);
}

// ---------------------------------------------------------------------
// FUSED prep: [zero deg | pack Bpk1 | pack Bpk2 | pack m1pk | cvt X->f16]
// ---------------------------------------------------------------------
__global__ __launch_bounds__(256) void prep_kernel(
    const float* __restrict__ W1, const float* __restrict__ root1,
    unsigned short* __restrict__ Bpk1,
    const float* __restrict__ W2, const float* __restrict__ root2,
    unsigned short* __restrict__ Bpk2,
    const float* __restrict__ m1w, unsigned short* __restrict__ m1pk,
    const float4* __restrict__ X, unsigned short* __restrict__ Xhf,
    int* __restrict__ deg, int N) {
  int nbZ = (N + 255) >> 8;
  int b = blockIdx.x, t = threadIdx.x;
  if (b < nbZ) {
    int i = b * 256 + t;
    if (i < N) deg[i] = 0;
    return;
  }
  b -= nbZ;
  if (b < 160) {                       // Bpk1: 64*640 = 160*256
    pack_b_dev(W1, root1, Bpk1, 9, b * 256 + t);
    return;
  }
  b -= 160;
  if (b < 416) {                       // Bpk2: 64*1664 = 416*256
    pack_b_dev(W2, root2, Bpk2, 25, b * 256 + t);
    return;
  }
  b -= 416;
  if (b < 16) {                        // m1pk: 64*64 = 16*256
    pack_b_dev(m1w, m1w, m1pk, 0, b * 256 + t);
    return;
  }
  b -= 16;
  {                                    // cvt X (fp32x4 -> f16x4)
    int i = b * 256 + t;
    if (i < N * 16) {
      float4 v = X[i];
      short4v o = {(short)f2h(v.x), (short)f2h(v.y),
                   (short)f2h(v.z), (short)f2h(v.w)};
      *(short4v*)&Xhf[i * 4] = o;
    }
  }
}

// ---------------------------------------------------------------------
// CSR build: hist -> blocksum -> blockscan (partials scanned inline).
// ---------------------------------------------------------------------
__global__ __launch_bounds__(256) void hist_kernel(
    const int* __restrict__ dst, int* __restrict__ deg, int nE) {
  int e = blockIdx.x * 256 + threadIdx.x;
  if (e < nE) atomicAdd(&deg[dst[e]], 1);
}

__global__ __launch_bounds__(256) void blocksum_kernel(
    const int* __restrict__ deg, int* __restrict__ partial, int N) {
  __shared__ int s[256];
  int t = threadIdx.x, i = blockIdx.x * 256 + t;
  s[t] = (i < N) ? deg[i] : 0;
  __syncthreads();
  for (int off = 128; off > 0; off >>= 1) {
    if (t < off) s[t] += s[t + off];
    __syncthreads();
  }
  if (t == 0) partial[blockIdx.x] = s[0];
}

// grid must equal nb (<=256 blocks; N=50000 -> 196).
__global__ __launch_bounds__(256) void blockscan_kernel(
    const int* __restrict__ deg, const int* __restrict__ partial,
    int* __restrict__ row_start, int* __restrict__ cursor,
    int N, int nE, int nb) {
  __shared__ int sp[256];
  __shared__ int s[256];
  __shared__ int base;
  int t = threadIdx.x, i = blockIdx.x * 256 + t;
  int pv = (t < nb) ? partial[t] : 0;
  sp[t] = pv;
  __syncthreads();
  for (int off = 1; off < 256; off <<= 1) {
    int x = (t >= off) ? sp[t - off] : 0;
    __syncthreads();
    sp[t] += x;
    __syncthreads();
  }
  if (t == blockIdx.x) base = sp[t] - pv;
  __syncthreads();
  int v = (i < N) ? deg[i] : 0;
  s[t] = v;
  __syncthreads();
  for (int off = 1; off < 256; off <<= 1) {
    int x = (t >= off) ? s[t - off] : 0;
    __syncthreads();
    s[t] += x;
    __syncthreads();
  }
  if (i < N) {
    int excl = s[t] - v + base;
    row_start[i] = excl;
    cursor[i] = excl;
  }
  if (i == 0) row_start[N] = nE;
}

// COMPACT 8-byte record per edge: x = f16(attr0*4) | f16(attr1*4)<<16,
// y = src*64. Same rounding point as R17 (cvt to f16 pre-basis), so
// bit-identical math; halves rec bytes AND register footprint (enables
// the gather pipeline that spilled with 16B recs in R12).
// 48 zero tail records cover the deep pipeline look-ahead (c0+32+15).
__global__ __launch_bounds__(256) void scatter_rec_kernel(
    const int* __restrict__ dst, const int* __restrict__ src,
    const float* __restrict__ attr, int* __restrict__ cursor,
    uint2* __restrict__ recS, int nE) {
  int e = blockIdx.x * 256 + threadIdx.x;
  if (e < 48) recS[nE + e] = make_uint2(0u, 0u);
  if (e >= nE) return;
  int pos = atomicAdd(&cursor[dst[e]], 1);
  float2 a = *(const float2*)&attr[2 * e];
  fp16x2_raw uv = __builtin_amdgcn_cvt_pkrtz(a.x * 4.f, a.y * 4.f);
  recS[pos] = make_uint2(__builtin_bit_cast(unsigned int, uv),
                         (unsigned int)(src[e] * 64));
}

// ---------------------------------------------------------------------
// FUSED spline layer (+ optional fused MLP head): block = 4 waves =
// NODES dst nodes, natural order, dynamic node claim via LDS counter.
// Phase 1: MFMA bucket-aggregate (32x32x16 f16). 8B recs; (u,v) pairs
//   built with the SAME v_perm trick as the X fragments; basis in
//   packed f16. PF=1 (layer 2): 1-iteration-ahead GATHER PIPELINE —
//   per chunk: issue next chunk's gathers (from resident recs), next
//   basis, load chunk+2 recs, then MFMA with operands issued a FULL
//   iteration ago (~400cy gather cover). R17 proved the kernel is
//   latency-bound on this chain (VALU 45->39% gave dur +3us); R12's
//   pipeline spilled only because 16B recs carried 64+ regs — 8B recs
//   fit the budget. PF=0 (layer 1): shallow proven path.
// Phase 2: h = ELU( (Z @ Bz) * inv + x @ Broot + b ), 3 acc chains.
// Phase 3 (HEAD=1): fused MLP head in-block (LDS reused from As).
// REGISTER BUDGET (gfx950 unified VGPR/AGPR file): acc=32 + rjn(16) +
// xv(8)+xvn(8) + A/An(8) ~= 90 of 128 cap @ MINW=4. MINW>4 spills
// (R7/R8). Spill sentinel: layer-2 WRITE_SIZE ~1.56 MB.
// NODES: layer2=12 (16 regressed R11; 10 regressed R14).
// ---------------------------------------------------------------------
template <int K, int K2, int OUTF16, int NODES, int GRP, int MINW, int PF, int HEAD>
__global__ __launch_bounds__(256, MINW) void spline_layer_kernel(
    const uint2* __restrict__ rec, const int* __restrict__ row_start,
    const unsigned short* __restrict__ Xhf, const unsigned short* __restrict__ Bpk,
    const float* __restrict__ bias, void* __restrict__ outv, int N, float uscale,
    const unsigned short* __restrict__ m1pk_g, const float* __restrict__ m1b_g,
    const float* __restrict__ m2w_g, const float* __restrict__ m2b_g) {
  constexpr int RZ = K2 * 64;          // bucket columns: 576 / 1600
  constexpr int AS = RZ + 8;           // LDS node-row stride (shorts)
  constexpr int NKZ = RZ / 32;         // 18 / 50
  constexpr int NKC = (K2 + 1) * 2;    // 20 / 52
  __shared__ unsigned short As[NODES * AS];
  __shared__ __align__(16) float invs[16];
  __shared__ int wcur;
  const int t = threadIdx.x, w = t >> 6, lane = t & 63;
  const int nodeBase = blockIdx.x * NODES;

  const int col = lane & 31, half = lane >> 5, col2 = col * 2;
  // hat-basis centers; col >= K2 killed via -1e9 center (f16 -inf ->
  // max(0, 1-inf) = 0; no NaN path)
  const float mi0f = (col < K2) ? (float)(col % K) : -1e9f;
  const float mi1f = (col < K2) ? (float)(col / K) : 0.f;
  const h2 nus2 = {(_Float16)(-uscale), (_Float16)(-uscale)};
  const h2 m0s2 = {(_Float16)mi0f, (_Float16)mi0f};
  const h2 m1s2 = {(_Float16)mi1f, (_Float16)mi1f};
  const h2 one2 = {(_Float16)1.f, (_Float16)1.f};
  const h2 zer2 = {(_Float16)0.f, (_Float16)0.f};

  if (t == 0) wcur = 0;
  if constexpr (NODES < 16) {   // init dup-row inv slots [NODES,16) (wave3)
    if (w == 3 && lane >= 48 + NODES) invs[lane - 48] = 1.0f;
  }
  __syncthreads();

  // ---------- phase 1: dynamic node claim, zbuild into LDS ----------
  int row;
  if (lane == 0) row = atomicAdd(&wcur, 1);
  row = __shfl(row, 0);
  while (row < NODES) {
    const int node = nodeBase + row;
    if (node < N) {
      floatx16 d0, d1;
#pragma unroll
      for (int i = 0; i < 16; ++i) { d0[i] = 0.f; d1[i] = 0.f; }

      const int beg = row_start[node], end = row_start[node + 1];
      if (lane == 0) invs[row] = 1.f / (float)max(end - beg, 1);

      // packed-f16 basis for chunk at cc0, from 8 recs rr[]
      auto basis = [&](const uint2* rr, int cc0) -> half8 {
        const bool fullc = (end - cc0 >= 16);
        const int rem = end - (cc0 + half * 8);
        unsigned int aw[4];
#pragma unroll
        for (int i = 0; i < 4; ++i) {
          unsigned int ux = __builtin_amdgcn_perm(rr[2 * i + 1].x, rr[2 * i].x,
                                                  0x05040100u);
          unsigned int uy = __builtin_amdgcn_perm(rr[2 * i + 1].x, rr[2 * i].x,
                                                  0x07060302u);
          h2 t0 = __builtin_bit_cast(h2, ux) * nus2 + m0s2;
          h2 t1 = __builtin_bit_cast(h2, uy) * nus2 + m1s2;
          h2 s0 = __builtin_elementwise_max(
                      one2 - __builtin_elementwise_abs(t0), zer2);
          h2 s1 = __builtin_elementwise_max(
                      one2 - __builtin_elementwise_abs(t1), zer2);
          h2 p = s0 * s1;
          unsigned int pw = __builtin_bit_cast(unsigned int, p);
          if (!fullc) {                 // tail mask (rare path)
            if (2 * i >= rem) pw = 0;
            else if (2 * i + 1 >= rem) pw &= 0xFFFFu;
          }
          aw[i] = pw;
        }
        uint4v Awv = {aw[0], aw[1], aw[2], aw[3]};
        return __builtin_bit_cast(half8, Awv);
      };
      auto mfma_step = [&](half8 A, const unsigned int* xvp,
                           floatx16& dd0, floatx16& dd1) {
        uint4v blo, bhi;
#pragma unroll
        for (int i = 0; i < 4; ++i) {
          blo[i] = __builtin_amdgcn_perm(xvp[2 * i + 1], xvp[2 * i], 0x05040100u);
          bhi[i] = __builtin_amdgcn_perm(xvp[2 * i + 1], xvp[2 * i], 0x07060302u);
        }
        dd0 = __builtin_amdgcn_mfma_f32_32x32x16_f16(
                  A, __builtin_bit_cast(half8, blo), dd0, 0, 0, 0);
        dd1 = __builtin_amdgcn_mfma_f32_32x32x16_f16(
                  A, __builtin_bit_cast(half8, bhi), dd1, 0, 0, 0);
      };

      if constexpr (PF) {
        // ---- 1-ahead gather pipeline ----
        const int ibh = beg + half * 8;
        uint2 rjn[8];
        unsigned int xv[8], xvn[8];
        half8 A, An;
#pragma unroll
        for (int j = 0; j < 8; ++j) rjn[j] = rec[ibh + j];
#pragma unroll
        for (int j = 0; j < 8; ++j)
          xv[j] = *(const unsigned int*)(Xhf + (int)rjn[j].y + col2);
        A = basis(rjn, beg);
#pragma unroll
        for (int j = 0; j < 8; ++j) rjn[j] = rec[ibh + 16 + j];
        for (int c0 = beg; c0 < end; c0 += 16) {
          // 1) issue NEXT chunk's gathers (rjn resident)
#pragma unroll
          for (int j = 0; j < 8; ++j)
            xvn[j] = *(const unsigned int*)(Xhf + (int)rjn[j].y + col2);
          // 2) NEXT chunk's basis (rjn then dead)
          An = basis(rjn, c0 + 16);
          // 3) chunk+2 recs (48-rec tail pad covers overrun)
#pragma unroll
          for (int j = 0; j < 8; ++j) rjn[j] = rec[c0 + 32 + half * 8 + j];
          // 4) MFMA with operands issued a FULL iteration ago
          mfma_step(A, xv, d0, d1);
          // 5) rotate
          A = An;
#pragma unroll
          for (int j = 0; j < 8; ++j) xv[j] = xvn[j];
        }
      } else {
        // ---- shallow path (layer 1) ----
        for (int c0 = beg; c0 < end; c0 += 16) {
          const int ib = c0 + half * 8;
          uint2 rj[8];
#pragma unroll
          for (int j = 0; j < 8; ++j) rj[j] = rec[ib + j];
          unsigned int xv[8];
#pragma unroll
          for (int j = 0; j < 8; ++j)
            xv[j] = *(const unsigned int*)(Xhf + (int)rj[j].y + col2);
          half8 A = basis(rj, c0);
          mfma_step(A, xv, d0, d1);
        }
      }

#pragma unroll
      for (int reg = 0; reg < 16; ++reg) {
        int r = (reg & 3) + 8 * (reg >> 2) + 4 * half;
        if (r < K2) {  // unscaled; features (2c,2c+1) at positions (2c,2c+1)
          fp16x2_raw z = __builtin_amdgcn_cvt_pkrtz(d0[reg], d1[reg]);
          *(unsigned int*)&As[row * AS + r * 64 + col2] =
              __builtin_bit_cast(unsigned int, z);
        }
      }
    } else {
      if (lane == 0) invs[row] = 1.0f;
      for (int i = lane; i < RZ / 2; i += 64)
        ((unsigned int*)&As[row * AS])[i] = 0;
    }
    if (lane == 0) row = atomicAdd(&wcur, 1);
    row = __shfl(row, 0);
  }
  __syncthreads();

  // ---------- phase 2: NODES x R x 64 GEMM + inv-scale + bias + ELU ----------
  const int mrow = lane & 15, q = lane >> 4;
  const int arow = (NODES < 16) ? min(mrow, NODES - 1) : mrow;  // dup rows
  const int anode = min(nodeBase + arow, N - 1);  // root-row source (clamped)
  floatx4 aZ0 = {0.f, 0.f, 0.f, 0.f};
  floatx4 aZ1 = {0.f, 0.f, 0.f, 0.f};
  floatx4 aR  = {0.f, 0.f, 0.f, 0.f};
#pragma unroll
  for (int kc0 = 0; kc0 < NKC; kc0 += GRP) {
    short8 av[GRP], bv[GRP];
#pragma unroll
    for (int u = 0; u < GRP; ++u) {
      const int kc = kc0 + u;
      if (kc < NKZ)
        av[u] = *(const short8*)&As[arow * AS + kc * 32 + q * 8];
      else
        av[u] = *(const short8*)&Xhf[(size_t)anode * 64 + (kc - NKZ) * 32 + q * 8];
      bv[u] = *(const short8*)&Bpk[(((size_t)kc * 4 + w) * 64 + lane) * 8];
    }
#pragma unroll
    for (int u = 0; u < GRP; ++u) {
      const int kc = kc0 + u;
      if (kc >= NKZ)
        aR = __builtin_amdgcn_mfma_f32_16x16x32_f16(
                 __builtin_bit_cast(half8, av[u]),
                 __builtin_bit_cast(half8, bv[u]), aR, 0, 0, 0);
      else if ((kc0 / GRP) & 1)
        aZ1 = __builtin_amdgcn_mfma_f32_16x16x32_f16(
                  __builtin_bit_cast(half8, av[u]),
                  __builtin_bit_cast(half8, bv[u]), aZ1, 0, 0, 0);
      else
        aZ0 = __builtin_amdgcn_mfma_f32_16x16x32_f16(
                  __builtin_bit_cast(half8, av[u]),
                  __builtin_bit_cast(half8, bv[u]), aZ0, 0, 0, 0);
    }
  }

  // D layout: col = lane&15 -> o_local, row = q*4+reg -> node_local
  const int o = w * 16 + mrow;
  const float bvs = bias[o];
  const floatx4 invv = *(const floatx4*)&invs[q * 4];

  if constexpr (HEAD) {
    // ---------- phase 3: fused MLP head ----------
    __syncthreads();                       // all phase-2 As reads complete
    unsigned short* Hs = As;               // [16][72] f16, rows<NODES valid
    unsigned short* Ts = As + 2048;        // [16][72] f16
    float* W2s = (float*)(As + 4096);      // [512]
    for (int i = t; i < 512; i += 256) W2s[i] = m2w_g[i];
#pragma unroll
    for (int reg = 0; reg < 4; ++reg) {
      int rloc = q * 4 + reg;
      int node = nodeBase + rloc;
      if (rloc < NODES && node < N) {
        float v = (aZ0[reg] + aZ1[reg]) * invv[reg] + aR[reg] + bvs;
        v = v > 0.f ? v : (expf(v) - 1.f);
        Hs[rloc * 72 + o] = f2h(v);
      }
    }
    __syncthreads();
    // m1: T = relu(H @ m1w + m1b); dup A rows give dup D rows >= NODES,
    // discarded at projection.
    floatx4 accT = {0.f, 0.f, 0.f, 0.f};
#pragma unroll
    for (int kc = 0; kc < 2; ++kc) {
      short8 a = *(const short8*)&Hs[arow * 72 + kc * 32 + q * 8];
      short8 b = *(const short8*)&m1pk_g[(((size_t)kc * 4 + w) * 64 + lane) * 8];
      accT = __builtin_amdgcn_mfma_f32_16x16x32_f16(
                 __builtin_bit_cast(half8, a),
                 __builtin_bit_cast(half8, b), accT, 0, 0, 0);
    }
    const float bT = m1b_g[o];
#pragma unroll
    for (int reg = 0; reg < 4; ++reg) {
      float v = accT[reg] + bT;
      Ts[(q * 4 + reg) * 72 + o] = f2h(v > 0.f ? v : 0.f);
    }
    __syncthreads();
    // 64 -> 8 projection with ReLU (NODES*8 outputs)
    if (t < NODES * 8) {
      int nl = t >> 3, c = t & 7;
      int node = nodeBase + nl;
      if (node < N) {
        float s = m2b_g[c];
        for (int d = 0; d < 64; ++d) s += h2f(Ts[nl * 72 + d]) * W2s[d * 8 + c];
        ((float*)outv)[(size_t)node * 8 + c] = s > 0.f ? s : 0.f;
      }
    }
  } else {
#pragma unroll
    for (int reg = 0; reg < 4; ++reg) {
      int rloc = q * 4 + reg;
      int node = nodeBase + rloc;
      if (rloc < NODES && node < N) {
        float v = (aZ0[reg] + aZ1[reg]) * invv[reg] + aR[reg] + bvs;
        v = v > 0.f ? v : (expf(v) - 1.f);
        if (OUTF16)
          ((unsigned short*)outv)[(size_t)node * 64 + o] = f2h(v);
        else
          ((float*)outv)[(size_t)node * 64 + o] = v;
      }
    }
  }
}

// ---------------------------------------------------------------------
extern "C" void kernel_launch(void* const* d_in, const int* in_sizes, int n_in,
                              void* d_out, int out_size, void* d_ws, size_t ws_size,
                              hipStream_t stream) {
  const float* x     = (const float*)d_in[0];
  const int*   ei    = (const int*)d_in[1];
  const float* attr  = (const float*)d_in[2];
  const float* W1    = (const float*)d_in[3];
  const float* root1 = (const float*)d_in[4];
  const float* b1    = (const float*)d_in[5];
  const float* W2    = (const float*)d_in[6];
  const float* root2 = (const float*)d_in[7];
  const float* b2    = (const float*)d_in[8];
  const float* m1w   = (const float*)d_in[9];
  const float* m1b   = (const float*)d_in[10];
  const float* m2w   = (const float*)d_in[11];
  const float* m2b   = (const float*)d_in[12];

  const int N  = in_sizes[0] / 64;
  const int nE = in_sizes[1] / 2;
  const int* src  = ei;
  const int* dstv = ei + nE;
  float* out = (float*)d_out;

  // workspace layout
  int* deg       = (int*)d_ws;              // N
  int* row_start = deg + N;                 // N+1
  int* cursor    = row_start + (N + 1);     // N
  int* partial   = cursor + N;              // 256
  char* pbase = (char*)(partial + 256);
  pbase = (char*)(((uintptr_t)pbase + 15) & ~(uintptr_t)15);
  uint2* recS = (uint2*)pbase;                            // (nE+48) * 8B
  unsigned short* Xhf  = (unsigned short*)(recS + nE + 48);  // N*64 f16
  unsigned short* h1hf = Xhf + (size_t)N * 64;            // N*64 f16
  unsigned short* Bpk1 = h1hf + (size_t)N * 64;           // 64 * 640
  unsigned short* Bpk2 = Bpk1 + 64 * 640;                 // 64 * 1664
  unsigned short* m1pk = Bpk2 + 64 * 1664;                // 64 * 64

  dim3 blk(256);
  int nbN  = (N + 255) / 256;
  int nbE  = (nE + 255) / 256;
  int nbF1 = (N + 15) / 16;
  int nbF2 = (N + 11) / 12;
  int nbP  = nbN + 160 + 416 + 16 + (N * 16 + 255) / 256;

  // ----- fused prep: zero deg + pack Bpk1/Bpk2/m1pk + cvt X (1 launch) -----
  prep_kernel<<<nbP, blk, 0, stream>>>(W1, root1, Bpk1, W2, root2, Bpk2,
                                       m1w, m1pk, (const float4*)x, Xhf,
                                       deg, N);

  // ----- CSR build (graph identical both layers) -----
  hist_kernel<<<nbE, blk, 0, stream>>>(dstv, deg, nE);
  blocksum_kernel<<<nbN, blk, 0, stream>>>(deg, partial, N);
  blockscan_kernel<<<nbN, blk, 0, stream>>>(deg, partial, row_start, cursor,
                                            N, nE, nbN);
  scatter_rec_kernel<<<nbE, blk, 0, stream>>>(dstv, src, attr, cursor, recS, nE);

  // ----- layer 1 (K=3, K2=9): 16 nodes/block, MINW=4, shallow path -----
  spline_layer_kernel<3, 9, 1, 16, 4, 4, 0, 0><<<nbF1, blk, 0, stream>>>(
      recS, row_start, Xhf, Bpk1, b1, h1hf, N, 0.5f,
      m1pk, m1b, m2w, m2b);

  // ----- layer 2 (K=5, K2=25): 12 nodes/block, MINW=4, gather pipeline,
  //       FUSED HEAD. Input is h1hf (layer-1 output), NOT Xhf.
  spline_layer_kernel<5, 25, 0, 12, 4, 4, 1, 1><<<nbF2, blk, 0, stream>>>(
      recS, row_start, h1hf, Bpk2, b2, out, N, 1.0f,
      m1pk, m1b, m2w, m2b);
}

// Round 19
// 278.926 us; speedup vs baseline: 1.0712x; 1.0712x over previous
//
#include <hip/hip_runtime.h>
#include <hip/hip_fp16.h>

typedef __attribute__((ext_vector_type(8))) short short8;
typedef __attribute__((ext_vector_type(4))) short short4v;
typedef __attribute__((ext_vector_type(4))) unsigned int uint4v;
typedef __attribute__((ext_vector_type(4))) float floatx4;
typedef __attribute__((ext_vector_type(16))) float floatx16;
typedef __fp16 fp16x2_raw __attribute__((ext_vector_type(2)));   // cvt_pkrtz ret
typedef _Float16 h2 __attribute__((ext_vector_type(2)));
typedef _Float16 half8 __attribute__((ext_vector_type(8)));

__device__ __forceinline__ unsigned short f2h(float x) {
  _Float16 h = (_Float16)x;
  return __builtin_bit_cast(unsigned short, h);
}
__device__ __forceinline__ float h2f(unsigned short u) {
  return (float)__builtin_bit_cast(_Float16, u);
}

// ---------------------------------------------------------------------
// Pack extended weights [W | root] into MFMA B-fragment order (flat i),
// as FP16. K-dim order IDENTITY. K2=0 packs a 64x64 matrix from root.
// ---------------------------------------------------------------------
__device__ __forceinline__ void pack_b_dev(
    const float* __restrict__ W, const float* __restrict__ root,
    unsigned short* __restrict__ Bpk, int K2, int i) {
  int j = i & 7;
  int lane = (i >> 3) & 63;
  int rest = i >> 9;            // kc*4 + wv
  int wv = rest & 3, kc = rest >> 2;
  int o = wv * 16 + (lane & 15);
  int p = kc * 32 + ((lane >> 4) & 3) * 8 + j;   // flat K position
  int k = p >> 6, q6 = p & 63;
  float v = (k < K2) ? W[(k << 12) + (q6 << 6) + o] : root[(q6 << 6) + o];
  Bpk[i] = f2h(v);
}

// ---------------------------------------------------------------------
// FUSED prep: [zero deg | pack Bpk1 | pack Bpk2 | pack m1pk | cvt X->f16]
// ---------------------------------------------------------------------
__global__ __launch_bounds__(256) void prep_kernel(
    const float* __restrict__ W1, const float* __restrict__ root1,
    unsigned short* __restrict__ Bpk1,
    const float* __restrict__ W2, const float* __restrict__ root2,
    unsigned short* __restrict__ Bpk2,
    const float* __restrict__ m1w, unsigned short* __restrict__ m1pk,
    const float4* __restrict__ X, unsigned short* __restrict__ Xhf,
    int* __restrict__ deg, int N) {
  int nbZ = (N + 255) >> 8;
  int b = blockIdx.x, t = threadIdx.x;
  if (b < nbZ) {
    int i = b * 256 + t;
    if (i < N) deg[i] = 0;
    return;
  }
  b -= nbZ;
  if (b < 160) {                       // Bpk1: 64*640 = 160*256
    pack_b_dev(W1, root1, Bpk1, 9, b * 256 + t);
    return;
  }
  b -= 160;
  if (b < 416) {                       // Bpk2: 64*1664 = 416*256
    pack_b_dev(W2, root2, Bpk2, 25, b * 256 + t);
    return;
  }
  b -= 416;
  if (b < 16) {                        // m1pk: 64*64 = 16*256
    pack_b_dev(m1w, m1w, m1pk, 0, b * 256 + t);
    return;
  }
  b -= 16;
  {                                    // cvt X (fp32x4 -> f16x4)
    int i = b * 256 + t;
    if (i < N * 16) {
      float4 v = X[i];
      short4v o = {(short)f2h(v.x), (short)f2h(v.y),
                   (short)f2h(v.z), (short)f2h(v.w)};
      *(short4v*)&Xhf[i * 4] = o;
    }
  }
}

// ---------------------------------------------------------------------
// CSR build: hist -> blocksum -> blockscan (partials scanned inline).
// ---------------------------------------------------------------------
__global__ __launch_bounds__(256) void hist_kernel(
    const int* __restrict__ dst, int* __restrict__ deg, int nE) {
  int e = blockIdx.x * 256 + threadIdx.x;
  if (e < nE) atomicAdd(&deg[dst[e]], 1);
}

__global__ __launch_bounds__(256) void blocksum_kernel(
    const int* __restrict__ deg, int* __restrict__ partial, int N) {
  __shared__ int s[256];
  int t = threadIdx.x, i = blockIdx.x * 256 + t;
  s[t] = (i < N) ? deg[i] : 0;
  __syncthreads();
  for (int off = 128; off > 0; off >>= 1) {
    if (t < off) s[t] += s[t + off];
    __syncthreads();
  }
  if (t == 0) partial[blockIdx.x] = s[0];
}

// grid must equal nb (<=256 blocks; N=50000 -> 196).
__global__ __launch_bounds__(256) void blockscan_kernel(
    const int* __restrict__ deg, const int* __restrict__ partial,
    int* __restrict__ row_start, int* __restrict__ cursor,
    int N, int nE, int nb) {
  __shared__ int sp[256];
  __shared__ int s[256];
  __shared__ int base;
  int t = threadIdx.x, i = blockIdx.x * 256 + t;
  int pv = (t < nb) ? partial[t] : 0;
  sp[t] = pv;
  __syncthreads();
  for (int off = 1; off < 256; off <<= 1) {
    int x = (t >= off) ? sp[t - off] : 0;
    __syncthreads();
    sp[t] += x;
    __syncthreads();
  }
  if (t == blockIdx.x) base = sp[t] - pv;
  __syncthreads();
  int v = (i < N) ? deg[i] : 0;
  s[t] = v;
  __syncthreads();
  for (int off = 1; off < 256; off <<= 1) {
    int x = (t >= off) ? s[t - off] : 0;
    __syncthreads();
    s[t] += x;
    __syncthreads();
  }
  if (i < N) {
    int excl = s[t] - v + base;
    row_start[i] = excl;
    cursor[i] = excl;
  }
  if (i == 0) row_start[N] = nE;
}

// COMPACT 8-byte record per edge: x = f16(attr0*4) | f16(attr1*4)<<16,
// y = src*64. Same rounding point as f16 basis (bit-identical math);
// halves rec bytes and register footprint.
// 32 zero tail records cover shallow-PF look-ahead (c0+16+15).
__global__ __launch_bounds__(256) void scatter_rec_kernel(
    const int* __restrict__ dst, const int* __restrict__ src,
    const float* __restrict__ attr, int* __restrict__ cursor,
    uint2* __restrict__ recS, int nE) {
  int e = blockIdx.x * 256 + threadIdx.x;
  if (e < 32) recS[nE + e] = make_uint2(0u, 0u);
  if (e >= nE) return;
  int pos = atomicAdd(&cursor[dst[e]], 1);
  float2 a = *(const float2*)&attr[2 * e];
  fp16x2_raw uv = __builtin_amdgcn_cvt_pkrtz(a.x * 4.f, a.y * 4.f);
  recS[pos] = make_uint2(__builtin_bit_cast(unsigned int, uv),
                         (unsigned int)(src[e] * 64));
}

// ---------------------------------------------------------------------
// FUSED spline layer (+ optional fused MLP head): block = 4 waves =
// NODES dst nodes, natural order, dynamic node claim via LDS counter.
// Row bounds for ALL the block's nodes are prefetched into LDS at block
// entry (coalesced, behind the existing barrier) — removes the ~300cy
// serial row_start load from the head of every node's chain.
// Phase 1: MFMA bucket-aggregate (32x32x16 f16). 8B recs; (u,v) pairs
//   via v_perm; basis in packed f16 (2 edges/instr). PF=1: SHALLOW
//   next-chunk rec prefetch (proven best; 1-ahead gather pipeline
//   regressed twice: R12 spilled, R18 +9% VALU from rotation copies).
// Phase 2: h = ELU( (Z @ Bz) * inv + x @ Broot + b ), 3 acc chains.
// Phase 3 (HEAD=1): fused MLP head in-block (LDS reused from As).
// REGISTER BUDGET (gfx950 unified VGPR/AGPR file): MINW stays 4 — all
// higher caps spill the 32-AGPR accumulators (R7/R8: 426/269 MB).
// Spill sentinel: layer-2 WRITE_SIZE ~1.56 MB.
// NODES: layer2=12 (16 regressed R11; 10 regressed R14).
// ---------------------------------------------------------------------
template <int K, int K2, int OUTF16, int NODES, int GRP, int MINW, int PF, int HEAD>
__global__ __launch_bounds__(256, MINW) void spline_layer_kernel(
    const uint2* __restrict__ rec, const int* __restrict__ row_start,
    const unsigned short* __restrict__ Xhf, const unsigned short* __restrict__ Bpk,
    const float* __restrict__ bias, void* __restrict__ outv, int N, float uscale,
    const unsigned short* __restrict__ m1pk_g, const float* __restrict__ m1b_g,
    const float* __restrict__ m2w_g, const float* __restrict__ m2b_g) {
  constexpr int RZ = K2 * 64;          // bucket columns: 576 / 1600
  constexpr int AS = RZ + 8;           // LDS node-row stride (shorts)
  constexpr int NKZ = RZ / 32;         // 18 / 50
  constexpr int NKC = (K2 + 1) * 2;    // 20 / 52
  __shared__ unsigned short As[NODES * AS];
  __shared__ __align__(16) float invs[16];
  __shared__ int rs[17];               // prefetched row bounds
  __shared__ int wcur;
  const int t = threadIdx.x, w = t >> 6, lane = t & 63;
  const int nodeBase = blockIdx.x * NODES;

  const int col = lane & 31, half = lane >> 5, col2 = col * 2;
  // hat-basis centers; col >= K2 killed via -1e9 center (f16 -inf ->
  // max(0, 1-inf) = 0; no NaN path)
  const float mi0f = (col < K2) ? (float)(col % K) : -1e9f;
  const float mi1f = (col < K2) ? (float)(col / K) : 0.f;
  const h2 nus2 = {(_Float16)(-uscale), (_Float16)(-uscale)};
  const h2 m0s2 = {(_Float16)mi0f, (_Float16)mi0f};
  const h2 m1s2 = {(_Float16)mi1f, (_Float16)mi1f};
  const h2 one2 = {(_Float16)1.f, (_Float16)1.f};
  const h2 zer2 = {(_Float16)0.f, (_Float16)0.f};

  if (t == 0) wcur = 0;
  if (t <= NODES) {                    // prefetch row bounds (coalesced)
    int idx = min(nodeBase + t, N);    // clamp; rows >= N unused
    rs[t] = row_start[idx];
  }
  if constexpr (NODES < 16) {   // init dup-row inv slots [NODES,16) (wave3)
    if (w == 3 && lane >= 48 + NODES) invs[lane - 48] = 1.0f;
  }
  __syncthreads();

  // ---------- phase 1: dynamic node claim, zbuild into LDS ----------
  int row;
  if (lane == 0) row = atomicAdd(&wcur, 1);
  row = __shfl(row, 0);
  while (row < NODES) {
    const int node = nodeBase + row;
    if (node < N) {
      floatx16 d0, d1;
#pragma unroll
      for (int i = 0; i < 16; ++i) { d0[i] = 0.f; d1[i] = 0.f; }

      const int beg = rs[row], end = rs[row + 1];
      if (lane == 0) invs[row] = 1.f / (float)max(end - beg, 1);

      // packed-f16 basis for chunk at cc0, from 8 recs rr[]
      auto basis = [&](const uint2* rr, int cc0) -> half8 {
        const bool fullc = (end - cc0 >= 16);
        const int rem = end - (cc0 + half * 8);
        unsigned int aw[4];
#pragma unroll
        for (int i = 0; i < 4; ++i) {
          unsigned int ux = __builtin_amdgcn_perm(rr[2 * i + 1].x, rr[2 * i].x,
                                                  0x05040100u);
          unsigned int uy = __builtin_amdgcn_perm(rr[2 * i + 1].x, rr[2 * i].x,
                                                  0x07060302u);
          h2 t0 = __builtin_bit_cast(h2, ux) * nus2 + m0s2;
          h2 t1 = __builtin_bit_cast(h2, uy) * nus2 + m1s2;
          h2 s0 = __builtin_elementwise_max(
                      one2 - __builtin_elementwise_abs(t0), zer2);
          h2 s1 = __builtin_elementwise_max(
                      one2 - __builtin_elementwise_abs(t1), zer2);
          h2 p = s0 * s1;
          unsigned int pw = __builtin_bit_cast(unsigned int, p);
          if (!fullc) {                 // tail mask (rare path)
            if (2 * i >= rem) pw = 0;
            else if (2 * i + 1 >= rem) pw &= 0xFFFFu;
          }
          aw[i] = pw;
        }
        uint4v Awv = {aw[0], aw[1], aw[2], aw[3]};
        return __builtin_bit_cast(half8, Awv);
      };

      uint2 rjn[8];
      if constexpr (PF) {
        const int ib0 = beg + half * 8;
#pragma unroll
        for (int j = 0; j < 8; ++j) rjn[j] = rec[ib0 + j];
      }
      for (int c0 = beg; c0 < end; c0 += 16) {
        uint2 rj[8];
        if constexpr (PF) {
#pragma unroll
          for (int j = 0; j < 8; ++j) rj[j] = rjn[j];
        } else {
          const int ib = c0 + half * 8;
#pragma unroll
          for (int j = 0; j < 8; ++j) rj[j] = rec[ib + j];
        }
        // 1) issue gathers first (addresses ready from prefetched recs)
        unsigned int xv[8];
#pragma unroll
        for (int j = 0; j < 8; ++j)
          xv[j] = *(const unsigned int*)(Xhf + (int)rj[j].y + col2);
        // 2) issue next chunk's rec loads (tail-padded by 32 records)
        if constexpr (PF) {
          const int ibn = c0 + 16 + half * 8;
#pragma unroll
          for (int j = 0; j < 8; ++j) rjn[j] = rec[ibn + j];
        }
        // 3) basis (packed f16; hides gather latency)
        half8 A = basis(rj, c0);
        // 4) perm + MFMA
        uint4v blo, bhi;
#pragma unroll
        for (int i = 0; i < 4; ++i) {
          blo[i] = __builtin_amdgcn_perm(xv[2 * i + 1], xv[2 * i], 0x05040100u);
          bhi[i] = __builtin_amdgcn_perm(xv[2 * i + 1], xv[2 * i], 0x07060302u);
        }
        d0 = __builtin_amdgcn_mfma_f32_32x32x16_f16(
                 A, __builtin_bit_cast(half8, blo), d0, 0, 0, 0);
        d1 = __builtin_amdgcn_mfma_f32_32x32x16_f16(
                 A, __builtin_bit_cast(half8, bhi), d1, 0, 0, 0);
      }

#pragma unroll
      for (int reg = 0; reg < 16; ++reg) {
        int r = (reg & 3) + 8 * (reg >> 2) + 4 * half;
        if (r < K2) {  // unscaled; features (2c,2c+1) at positions (2c,2c+1)
          fp16x2_raw z = __builtin_amdgcn_cvt_pkrtz(d0[reg], d1[reg]);
          *(unsigned int*)&As[row * AS + r * 64 + col2] =
              __builtin_bit_cast(unsigned int, z);
        }
      }
    } else {
      if (lane == 0) invs[row] = 1.0f;
      for (int i = lane; i < RZ / 2; i += 64)
        ((unsigned int*)&As[row * AS])[i] = 0;
    }
    if (lane == 0) row = atomicAdd(&wcur, 1);
    row = __shfl(row, 0);
  }
  __syncthreads();

  // ---------- phase 2: NODES x R x 64 GEMM + inv-scale + bias + ELU ----------
  const int mrow = lane & 15, q = lane >> 4;
  const int arow = (NODES < 16) ? min(mrow, NODES - 1) : mrow;  // dup rows
  const int anode = min(nodeBase + arow, N - 1);  // root-row source (clamped)
  floatx4 aZ0 = {0.f, 0.f, 0.f, 0.f};
  floatx4 aZ1 = {0.f, 0.f, 0.f, 0.f};
  floatx4 aR  = {0.f, 0.f, 0.f, 0.f};
#pragma unroll
  for (int kc0 = 0; kc0 < NKC; kc0 += GRP) {
    short8 av[GRP], bv[GRP];
#pragma unroll
    for (int u = 0; u < GRP; ++u) {
      const int kc = kc0 + u;
      if (kc < NKZ)
        av[u] = *(const short8*)&As[arow * AS + kc * 32 + q * 8];
      else
        av[u] = *(const short8*)&Xhf[(size_t)anode * 64 + (kc - NKZ) * 32 + q * 8];
      bv[u] = *(const short8*)&Bpk[(((size_t)kc * 4 + w) * 64 + lane) * 8];
    }
#pragma unroll
    for (int u = 0; u < GRP; ++u) {
      const int kc = kc0 + u;
      if (kc >= NKZ)
        aR = __builtin_amdgcn_mfma_f32_16x16x32_f16(
                 __builtin_bit_cast(half8, av[u]),
                 __builtin_bit_cast(half8, bv[u]), aR, 0, 0, 0);
      else if ((kc0 / GRP) & 1)
        aZ1 = __builtin_amdgcn_mfma_f32_16x16x32_f16(
                  __builtin_bit_cast(half8, av[u]),
                  __builtin_bit_cast(half8, bv[u]), aZ1, 0, 0, 0);
      else
        aZ0 = __builtin_amdgcn_mfma_f32_16x16x32_f16(
                  __builtin_bit_cast(half8, av[u]),
                  __builtin_bit_cast(half8, bv[u]), aZ0, 0, 0, 0);
    }
  }

  // D layout: col = lane&15 -> o_local, row = q*4+reg -> node_local
  const int o = w * 16 + mrow;
  const float bvs = bias[o];
  const floatx4 invv = *(const floatx4*)&invs[q * 4];

  if constexpr (HEAD) {
    // ---------- phase 3: fused MLP head ----------
    __syncthreads();                       // all phase-2 As reads complete
    unsigned short* Hs = As;               // [16][72] f16, rows<NODES valid
    unsigned short* Ts = As + 2048;        // [16][72] f16
    float* W2s = (float*)(As + 4096);      // [512]
    for (int i = t; i < 512; i += 256) W2s[i] = m2w_g[i];
#pragma unroll
    for (int reg = 0; reg < 4; ++reg) {
      int rloc = q * 4 + reg;
      int node = nodeBase + rloc;
      if (rloc < NODES && node < N) {
        float v = (aZ0[reg] + aZ1[reg]) * invv[reg] + aR[reg] + bvs;
        v = v > 0.f ? v : (expf(v) - 1.f);
        Hs[rloc * 72 + o] = f2h(v);
      }
    }
    __syncthreads();
    // m1: T = relu(H @ m1w + m1b); dup A rows give dup D rows >= NODES,
    // discarded at projection.
    floatx4 accT = {0.f, 0.f, 0.f, 0.f};
#pragma unroll
    for (int kc = 0; kc < 2; ++kc) {
      short8 a = *(const short8*)&Hs[arow * 72 + kc * 32 + q * 8];
      short8 b = *(const short8*)&m1pk_g[(((size_t)kc * 4 + w) * 64 + lane) * 8];
      accT = __builtin_amdgcn_mfma_f32_16x16x32_f16(
                 __builtin_bit_cast(half8, a),
                 __builtin_bit_cast(half8, b), accT, 0, 0, 0);
    }
    const float bT = m1b_g[o];
#pragma unroll
    for (int reg = 0; reg < 4; ++reg) {
      float v = accT[reg] + bT;
      Ts[(q * 4 + reg) * 72 + o] = f2h(v > 0.f ? v : 0.f);
    }
    __syncthreads();
    // 64 -> 8 projection with ReLU (NODES*8 outputs)
    if (t < NODES * 8) {
      int nl = t >> 3, c = t & 7;
      int node = nodeBase + nl;
      if (node < N) {
        float s = m2b_g[c];
        for (int d = 0; d < 64; ++d) s += h2f(Ts[nl * 72 + d]) * W2s[d * 8 + c];
        ((float*)outv)[(size_t)node * 8 + c] = s > 0.f ? s : 0.f;
      }
    }
  } else {
#pragma unroll
    for (int reg = 0; reg < 4; ++reg) {
      int rloc = q * 4 + reg;
      int node = nodeBase + rloc;
      if (rloc < NODES && node < N) {
        float v = (aZ0[reg] + aZ1[reg]) * invv[reg] + aR[reg] + bvs;
        v = v > 0.f ? v : (expf(v) - 1.f);
        if (OUTF16)
          ((unsigned short*)outv)[(size_t)node * 64 + o] = f2h(v);
        else
          ((float*)outv)[(size_t)node * 64 + o] = v;
      }
    }
  }
}

// ---------------------------------------------------------------------
extern "C" void kernel_launch(void* const* d_in, const int* in_sizes, int n_in,
                              void* d_out, int out_size, void* d_ws, size_t ws_size,
                              hipStream_t stream) {
  const float* x     = (const float*)d_in[0];
  const int*   ei    = (const int*)d_in[1];
  const float* attr  = (const float*)d_in[2];
  const float* W1    = (const float*)d_in[3];
  const float* root1 = (const float*)d_in[4];
  const float* b1    = (const float*)d_in[5];
  const float* W2    = (const float*)d_in[6];
  const float* root2 = (const float*)d_in[7];
  const float* b2    = (const float*)d_in[8];
  const float* m1w   = (const float*)d_in[9];
  const float* m1b   = (const float*)d_in[10];
  const float* m2w   = (const float*)d_in[11];
  const float* m2b   = (const float*)d_in[12];

  const int N  = in_sizes[0] / 64;
  const int nE = in_sizes[1] / 2;
  const int* src  = ei;
  const int* dstv = ei + nE;
  float* out = (float*)d_out;

  // workspace layout
  int* deg       = (int*)d_ws;              // N
  int* row_start = deg + N;                 // N+1
  int* cursor    = row_start + (N + 1);     // N
  int* partial   = cursor + N;              // 256
  char* pbase = (char*)(partial + 256);
  pbase = (char*)(((uintptr_t)pbase + 15) & ~(uintptr_t)15);
  uint2* recS = (uint2*)pbase;                            // (nE+32) * 8B
  unsigned short* Xhf  = (unsigned short*)(recS + nE + 32);  // N*64 f16
  unsigned short* h1hf = Xhf + (size_t)N * 64;            // N*64 f16
  unsigned short* Bpk1 = h1hf + (size_t)N * 64;           // 64 * 640
  unsigned short* Bpk2 = Bpk1 + 64 * 640;                 // 64 * 1664
  unsigned short* m1pk = Bpk2 + 64 * 1664;                // 64 * 64

  dim3 blk(256);
  int nbN  = (N + 255) / 256;
  int nbE  = (nE + 255) / 256;
  int nbF1 = (N + 15) / 16;
  int nbF2 = (N + 11) / 12;
  int nbP  = nbN + 160 + 416 + 16 + (N * 16 + 255) / 256;

  // ----- fused prep: zero deg + pack Bpk1/Bpk2/m1pk + cvt X (1 launch) -----
  prep_kernel<<<nbP, blk, 0, stream>>>(W1, root1, Bpk1, W2, root2, Bpk2,
                                       m1w, m1pk, (const float4*)x, Xhf,
                                       deg, N);

  // ----- CSR build (graph identical both layers) -----
  hist_kernel<<<nbE, blk, 0, stream>>>(dstv, deg, nE);
  blocksum_kernel<<<nbN, blk, 0, stream>>>(deg, partial, N);
  blockscan_kernel<<<nbN, blk, 0, stream>>>(deg, partial, row_start, cursor,
                                            N, nE, nbN);
  scatter_rec_kernel<<<nbE, blk, 0, stream>>>(dstv, src, attr, cursor, recS, nE);

  // ----- layer 1 (K=3, K2=9): 16 nodes/block, MINW=4, shallow PF=0 -----
  spline_layer_kernel<3, 9, 1, 16, 4, 4, 0, 0><<<nbF1, blk, 0, stream>>>(
      recS, row_start, Xhf, Bpk1, b1, h1hf, N, 0.5f,
      m1pk, m1b, m2w, m2b);

  // ----- layer 2 (K=5, K2=25): 12 nodes/block, MINW=4, shallow PF=1,
  //       FUSED HEAD. Input is h1hf (layer-1 output), NOT Xhf.
  spline_layer_kernel<5, 25, 0, 12, 4, 4, 1, 1><<<nbF2, blk, 0, stream>>>(
      recS, row_start, h1hf, Bpk2, b2, out, N, 1.0f,
      m1pk, m1b, m2w, m2b);
}